// Round 2
// baseline (916.604 us; speedup 1.0000x reference)
//
#include <hip/hip_runtime.h>
#include <stdint.h>

// ---------------------------------------------------------------------------
// SigmoidAttentionJoiner on MI355X (gfx950)
// M = N*T*S = 16*512*5 = 40960 rows, J = 512, V = 2000 (padded to 2048)
// All GEMMs: bf16 MFMA 16x16x32, 128x128 tile, BK=32, 256 threads (2x2 waves,
// each wave 64x64 via 4x4 fragment grid) — m97-style structure.
//
// R2: - enc/dec inputs pre-converted fp32->bf16 in the fused prep kernel;
//       ALL GEMMs now use pure global_load_lds staging (A32 VALU-staging path
//       deleted — it was VALU-throughput-bound at ~2.5x the MFMA budget).
//     - prep = weight-conv + LN-prep + stats-zero + input-conv (one launch).
//     - XCD swizzle kept ONLY on the Wout GEMM (HBM-bound); N=512 GEMMs are
//       L3-resident where swizzle measures ~-2%.
// ---------------------------------------------------------------------------

typedef __attribute__((ext_vector_type(8))) __bf16 bf16x8;
typedef __attribute__((ext_vector_type(4))) float float4v;
typedef __attribute__((ext_vector_type(8))) unsigned short ushort8;

static constexpr int M_TOT = 16 * 512 * 5;   // 40960
static constexpr int JDIM  = 512;
static constexpr int VOUT  = 2000;
static constexpr int VPAD  = 2048;

#define DI __device__ __forceinline__

DI float bf2f(unsigned short u) {
    union { unsigned int i; float f; } w; w.i = ((unsigned int)u) << 16; return w.f;
}
DI unsigned short f2bf(float f) {
    union { float f; unsigned int i; } w; w.f = f;
    return (unsigned short)((w.i + 0x8000u) >> 16);   // round-to-nearest (ties away)
}

// async global->LDS, 16B per lane. LDS dest is wave-uniform base + lane*16,
// our chunk indexing is exactly lane-contiguous so this is safe (m104 caveat).
DI void gld_lds16(const void* g, void* l) {
    __builtin_amdgcn_global_load_lds(
        reinterpret_cast<__attribute__((address_space(1))) void*>(
            reinterpret_cast<uintptr_t>(g)),
        reinterpret_cast<__attribute__((address_space(3))) void*>(
            reinterpret_cast<uintptr_t>(l)),
        16, 0, 0);
}

// ---------------------------------------------------------------------------
// GEMM: C[m,n] = sum_k A[m,k] * B[n,k] (+ epilogue)   (B^T layout = (out,in))
// EPI 2: store bf16 tanh(dres + acc + bias), ld = 512
// EPI 3: store fp32 acc + bias, ld = NOUT, mask col < NOUT (grid padded)
// EPI 4: LN-affine: store bf16( rstd*acc + (-mu*rstd)*rs[col] + bias[col] )
// EPI 6: store bf16(acc + bias); accumulate row sum/ssq into st_sum/st_ssq
// ---------------------------------------------------------------------------
template <int EPI, int NOUT, bool SWZ>
__global__ __launch_bounds__(256) void gemm_bt(
    const unsigned short* __restrict__ A, const unsigned short* __restrict__ B,
    const float* __restrict__ bias, void* __restrict__ Cp,
    const unsigned short* __restrict__ dres,
    float* __restrict__ st_sum, float* __restrict__ st_ssq,
    const float* __restrict__ rs)
{
    constexpr int K = 512;
    constexpr int BM = 128, BN = 128, BK = 32;
    __shared__ unsigned short As[BM * BK];
    __shared__ unsigned short Bs[BN * BK];

    const int tid  = threadIdx.x;
    const int wave = tid >> 6;
    const int lane = tid & 63;
    const int wm   = wave >> 1;      // 0..1
    const int wn   = wave & 1;       // 0..1
    const int quad = lane >> 4;      // 0..3
    const int l16  = lane & 15;

    const int gx = gridDim.x;
    const int id = blockIdx.x + gx * blockIdx.y;
    int logical;
    if constexpr (SWZ) {
        // XCD-chunked bijective swizzle (nwg % 8 == 0)
        const int nwg = gx * gridDim.y;
        logical = (id & 7) * (nwg >> 3) + (id >> 3);
    } else {
        logical = id;
    }
    const int m0 = (logical / gx) * BM;
    const int n0 = (logical % gx) * BN;

    float4v acc[4][4];
#pragma unroll
    for (int i = 0; i < 4; i++)
#pragma unroll
        for (int j = 0; j < 4; j++)
            acc[i][j] = {0.f, 0.f, 0.f, 0.f};

    // staging chunks: 512 chunks of 8 elems per tile; thread covers c and c+256
    const int c0 = tid, c1 = tid + 256;
    const int ar0 = c0 >> 2, ac0 = (c0 & 3) * 8;
    const int ar1 = c1 >> 2, ac1 = (c1 & 3) * 8;

    for (int k0 = 0; k0 < K; k0 += BK) {
        gld_lds16(&B[(size_t)(n0 + ar0) * K + k0 + ac0], &Bs[c0 * 8]);
        gld_lds16(&B[(size_t)(n0 + ar1) * K + k0 + ac1], &Bs[c1 * 8]);
        gld_lds16(&A[(size_t)(m0 + ar0) * K + k0 + ac0], &As[c0 * 8]);
        gld_lds16(&A[(size_t)(m0 + ar1) * K + k0 + ac1], &As[c1 * 8]);
        __syncthreads();

        bf16x8 af[4], bfv[4];
#pragma unroll
        for (int i = 0; i < 4; i++)
            af[i] = *reinterpret_cast<const bf16x8*>(
                &As[(wm * 64 + i * 16 + l16) * BK + quad * 8]);
#pragma unroll
        for (int j = 0; j < 4; j++)
            bfv[j] = *reinterpret_cast<const bf16x8*>(
                &Bs[(wn * 64 + j * 16 + l16) * BK + quad * 8]);
#pragma unroll
        for (int i = 0; i < 4; i++)
#pragma unroll
            for (int j = 0; j < 4; j++)
                acc[i][j] = __builtin_amdgcn_mfma_f32_16x16x32_bf16(
                    af[i], bfv[j], acc[i][j], 0, 0, 0);
        __syncthreads();
    }

    float bias_v[4], rs_v[4];
#pragma unroll
    for (int j = 0; j < 4; j++) {
        int col = n0 + wn * 64 + j * 16 + l16;
        bias_v[j] = (col < NOUT) ? bias[col] : 0.f;
        if constexpr (EPI == 4) rs_v[j] = rs[col];
    }

    if constexpr (EPI == 4) {
        // LN folded: val = rstd*acc + (-mu*rstd)*rs[col] + b'[col]
#pragma unroll
        for (int i = 0; i < 4; i++) {
            int rbase = m0 + wm * 64 + i * 16 + quad * 4;
#pragma unroll
            for (int r = 0; r < 4; r++) {
                int row = rbase + r;
                float s  = st_sum[row];
                float s2 = st_ssq[row];
                float mean = s * (1.f / 512.f);
                float var  = s2 * (1.f / 512.f) - mean * mean;
                float rstd = rsqrtf(var + 1e-5f);
                float crow = -mean * rstd;
#pragma unroll
                for (int j = 0; j < 4; j++) {
                    int col = n0 + wn * 64 + j * 16 + l16;
                    float val = fmaf(rstd, acc[i][j][r],
                                fmaf(crow, rs_v[j], bias_v[j]));
                    ((unsigned short*)Cp)[(size_t)row * NOUT + col] = f2bf(val);
                }
            }
        }
    } else {
#pragma unroll
        for (int i = 0; i < 4; i++) {
            int rbase = m0 + wm * 64 + i * 16 + quad * 4;
#pragma unroll
            for (int j = 0; j < 4; j++) {
                int col = n0 + wn * 64 + j * 16 + l16;
#pragma unroll
                for (int r = 0; r < 4; r++) {
                    float val = acc[i][j][r] + bias_v[j];
                    int row = rbase + r;
                    if constexpr (EPI == 2) {
                        float d = bf2f(dres[(size_t)row * 512 + col]);
                        ((unsigned short*)Cp)[(size_t)row * 512 + col] = f2bf(tanhf(d + val));
                    } else if constexpr (EPI == 3) {
                        if (col < NOUT)
                            ((float*)Cp)[(size_t)row * NOUT + col] = val;
                    } else {  // EPI == 6
                        ((unsigned short*)Cp)[(size_t)row * NOUT + col] = f2bf(val);
                    }
                }
            }
        }
    }

    if constexpr (EPI == 6) {
        // row partial sums over this block's 128 cols -> global atomics
#pragma unroll
        for (int i = 0; i < 4; i++) {
#pragma unroll
            for (int r = 0; r < 4; r++) {
                float ps = 0.f, ps2 = 0.f;
#pragma unroll
                for (int j = 0; j < 4; j++) {
                    float v = acc[i][j][r] + bias_v[j];
                    ps += v;
                    ps2 = fmaf(v, v, ps2);
                }
#pragma unroll
                for (int m = 1; m < 16; m <<= 1) {
                    ps  += __shfl_xor(ps,  m, 64);
                    ps2 += __shfl_xor(ps2, m, 64);
                }
                if (l16 == 0) {
                    int row = m0 + wm * 64 + i * 16 + quad * 4 + r;
                    atomicAdd(&st_sum[row], ps);
                    atomicAdd(&st_ssq[row], ps2);
                }
            }
        }
    }
}

// ---------------------------------------------------------------------------
// Fused prep:
//   blocks [0,768):      six 512x512 weights -> bf16 (Wq*g_q, Wk/Wv*g_kv)
//   blocks [768,1280):   Wout (2000x512, zero-pad to 2048) -> bf16
//   blocks [0,640):      also zero the 163840-float row-stats region
//   blocks [1280,11520): enc_in fp32 -> bf16
//   blocks [11520,21760):dec_in fp32 -> bf16
//   blocks [21760,22144):LN-fold prep (rs = W·g, b' = b + W·beta), 1536 waves
// ---------------------------------------------------------------------------
__global__ __launch_bounds__(256) void prep_kernel(
    const float* __restrict__ We, const float* __restrict__ Wd,
    const float* __restrict__ Wq, const float* __restrict__ Wk,
    const float* __restrict__ Wv, const float* __restrict__ Wo,
    const float* __restrict__ Wout,
    const float* __restrict__ g_q, const float* __restrict__ beta_q,
    const float* __restrict__ g_kv, const float* __restrict__ beta_kv,
    const float* __restrict__ bq, const float* __restrict__ bk,
    const float* __restrict__ bv,
    const float* __restrict__ enc_in, const float* __restrict__ dec_in,
    unsigned short* __restrict__ WB,
    unsigned short* __restrict__ encB, unsigned short* __restrict__ decB,
    float* __restrict__ stz,
    float* __restrict__ rs_q, float* __restrict__ b_q,
    float* __restrict__ rs_kv, float* __restrict__ b_kv)
{
    const int b   = blockIdx.x;
    const int tid = threadIdx.x;

    if (b < 1280) {
        // ---- weights ----
        if (b < 768) {
            const int seg = b >> 7;                      // 0..5
            const int off = (b & 127) * 2048 + tid * 8;  // within 512x512
            const float* src = seg == 0 ? We : seg == 1 ? Wd : seg == 2 ? Wq
                             : seg == 3 ? Wk : seg == 4 ? Wv : Wo;
            float4 f0 = *(const float4*)&src[off];
            float4 f1 = *(const float4*)&src[off + 4];
            float sc[8] = {1,1,1,1,1,1,1,1};
            if (seg >= 2 && seg <= 4) {
                const float* g = (seg == 2) ? g_q : g_kv;
                int j0 = off & 511;
                float4 s0 = *(const float4*)&g[j0];
                float4 s1 = *(const float4*)&g[j0 + 4];
                sc[0]=s0.x; sc[1]=s0.y; sc[2]=s0.z; sc[3]=s0.w;
                sc[4]=s1.x; sc[5]=s1.y; sc[6]=s1.z; sc[7]=s1.w;
            }
            ushort8 u;
            u[0]=f2bf(f0.x*sc[0]); u[1]=f2bf(f0.y*sc[1]); u[2]=f2bf(f0.z*sc[2]); u[3]=f2bf(f0.w*sc[3]);
            u[4]=f2bf(f1.x*sc[4]); u[5]=f2bf(f1.y*sc[5]); u[6]=f2bf(f1.z*sc[6]); u[7]=f2bf(f1.w*sc[7]);
            *reinterpret_cast<ushort8*>(&WB[(size_t)b * 2048 + tid * 8]) = u;
        } else {
            // Wout region: 2048x512 bf16, rows >= 2000 zero
            const int rem = (b - 768) * 2048 + tid * 8;
            const int row = rem >> 9;
            ushort8 u;
            if (row < VOUT) {
                float4 f0 = *(const float4*)&Wout[rem];
                float4 f1 = *(const float4*)&Wout[rem + 4];
                u[0]=f2bf(f0.x); u[1]=f2bf(f0.y); u[2]=f2bf(f0.z); u[3]=f2bf(f0.w);
                u[4]=f2bf(f1.x); u[5]=f2bf(f1.y); u[6]=f2bf(f1.z); u[7]=f2bf(f1.w);
            } else {
                u = (ushort8)0;
            }
            *reinterpret_cast<ushort8*>(&WB[1572864 + (size_t)(b - 768) * 2048 + tid * 8]) = u;
        }
        int z = b * 256 + tid;
        if (z < 163840) stz[z] = 0.f;
    } else if (b < 21760) {
        // ---- enc/dec fp32 -> bf16 ----
        const bool isDec = b >= 11520;
        const int  cb    = b - (isDec ? 11520 : 1280);
        const float* src = isDec ? dec_in : enc_in;
        unsigned short* dst = isDec ? decB : encB;
        const size_t base = (size_t)cb * 2048 + tid * 8;
        float4 f0 = *(const float4*)&src[base];
        float4 f1 = *(const float4*)&src[base + 4];
        ushort8 u;
        u[0]=f2bf(f0.x); u[1]=f2bf(f0.y); u[2]=f2bf(f0.z); u[3]=f2bf(f0.w);
        u[4]=f2bf(f1.x); u[5]=f2bf(f1.y); u[6]=f2bf(f1.z); u[7]=f2bf(f1.w);
        *reinterpret_cast<ushort8*>(&dst[base]) = u;
    } else {
        // ---- LN-fold prep: one wave per output row ----
        const int idx  = (b - 21760) * 4 + (tid >> 6);   // 0..1535
        const int lane = tid & 63;
        const float *W, *g, *bt, *bb; float *rs_out, *b_out; int r;
        if (idx < 512)       { W = Wq; g = g_q;  bt = beta_q;  bb = bq;
                               rs_out = &rs_q[idx];        b_out = &b_q[idx];        r = idx; }
        else if (idx < 1024) { W = Wk; g = g_kv; bt = beta_kv; bb = bk;
                               rs_out = &rs_kv[idx - 512]; b_out = &b_kv[idx - 512]; r = idx - 512; }
        else                 { W = Wv; g = g_kv; bt = beta_kv; bb = bv;
                               rs_out = &rs_kv[idx - 512]; b_out = &b_kv[idx - 512]; r = idx - 1024; }

        const float* wr = &W[(size_t)r * 512];
        float s = 0.f, sb = 0.f;
        int j0 = lane * 8;
        float4 w0 = *(const float4*)&wr[j0];
        float4 w1 = *(const float4*)&wr[j0 + 4];
        float4 ga = *(const float4*)&g[j0];
        float4 gb = *(const float4*)&g[j0 + 4];
        float4 ba = *(const float4*)&bt[j0];
        float4 bb4 = *(const float4*)&bt[j0 + 4];
        s  += w0.x * ga.x + w0.y * ga.y + w0.z * ga.z + w0.w * ga.w;
        s  += w1.x * gb.x + w1.y * gb.y + w1.z * gb.z + w1.w * gb.w;
        sb += w0.x * ba.x + w0.y * ba.y + w0.z * ba.z + w0.w * ba.w;
        sb += w1.x * bb4.x + w1.y * bb4.y + w1.z * bb4.z + w1.w * bb4.w;
#pragma unroll
        for (int m = 1; m < 64; m <<= 1) {
            s  += __shfl_xor(s,  m, 64);
            sb += __shfl_xor(sb, m, 64);
        }
        if (lane == 0) { *rs_out = s; *b_out = bb[r] + sb; }
    }
}

// ---------------------------------------------------------------------------
// framewise sigmoid attention: one wave per row; head h = lanes [8h, 8h+8)
// kv layout: [row][0..512) = k, [row][512..1024) = v
// ---------------------------------------------------------------------------
__global__ __launch_bounds__(256) void attn_kernel(
    const unsigned short* __restrict__ q, const unsigned short* __restrict__ kv,
    unsigned short* __restrict__ ctx)
{
    int row  = blockIdx.x * 4 + (threadIdx.x >> 6);
    int lane = threadIdx.x & 63;
    size_t qoff = (size_t)row * 512 + lane * 8;
    size_t kvo  = (size_t)row * 1024 + lane * 8;
    ushort8 uq = *reinterpret_cast<const ushort8*>(&q[qoff]);
    ushort8 uk = *reinterpret_cast<const ushort8*>(&kv[kvo]);
    float dot = 0.f;
#pragma unroll
    for (int j = 0; j < 8; j++) dot += bf2f(uq[j]) * bf2f(uk[j]);
    dot += __shfl_xor(dot, 1, 64);
    dot += __shfl_xor(dot, 2, 64);
    dot += __shfl_xor(dot, 4, 64);
    float sg = 1.f / (1.f + __expf(-dot * 0.125f));
    ushort8 uv = *reinterpret_cast<const ushort8*>(&kv[kvo + 512]);
    ushort8 o;
#pragma unroll
    for (int j = 0; j < 8; j++) o[j] = f2bf(sg * bf2f(uv[j]));
    *reinterpret_cast<ushort8*>(&ctx[qoff]) = o;
}

// ---------------------------------------------------------------------------
extern "C" void kernel_launch(void* const* d_in, const int* in_sizes, int n_in,
                              void* d_out, int out_size, void* d_ws, size_t ws_size,
                              hipStream_t stream)
{
    (void)in_sizes; (void)n_in; (void)out_size; (void)ws_size;
    const float* enc_in  = (const float*)d_in[0];
    const float* dec_in  = (const float*)d_in[1];
    const float* We      = (const float*)d_in[2];  const float* be     = (const float*)d_in[3];
    const float* Wd      = (const float*)d_in[4];  const float* bd     = (const float*)d_in[5];
    const float* g_q     = (const float*)d_in[6];  const float* beta_q = (const float*)d_in[7];
    const float* g_kv    = (const float*)d_in[8];  const float* beta_kv= (const float*)d_in[9];
    const float* Wq      = (const float*)d_in[10]; const float* bq     = (const float*)d_in[11];
    const float* Wk      = (const float*)d_in[12]; const float* bk     = (const float*)d_in[13];
    const float* Wv      = (const float*)d_in[14]; const float* bv     = (const float*)d_in[15];
    const float* Wo      = (const float*)d_in[16]; const float* bo     = (const float*)d_in[17];
    const float* Wout    = (const float*)d_in[18]; const float* bout   = (const float*)d_in[19];
    float* out = (float*)d_out;

    // bf16 weight buffer layout (elements)
    unsigned short* WB    = (unsigned short*)d_ws;
    unsigned short* WeB   = WB + 0;
    unsigned short* WdB   = WB + 262144;
    unsigned short* WqB   = WB + 524288;
    unsigned short* WkB   = WB + 786432;   // Wk then Wv contiguous => KV B, N=1024
    unsigned short* WoB   = WB + 1310720;
    unsigned short* WoutB = WB + 1572864;  // 2048 x 512 (zero-padded rows)

    // eight aliased M x 512 bf16 slots
    char* sbase = (char*)d_ws + 5242880;
    const size_t SZ = (size_t)M_TOT * 512 * 2;   // 41,943,040 B
    unsigned short* EB = (unsigned short*)(sbase + 0 * SZ);  // enc bf16
    unsigned short* DB = (unsigned short*)(sbase + 1 * SZ);  // dec bf16
    unsigned short* S0 = (unsigned short*)(sbase + 2 * SZ);  // encO
    unsigned short* S1 = (unsigned short*)(sbase + 3 * SZ);  // decO (live to tanh)
    unsigned short* S2 = (unsigned short*)(sbase + 4 * SZ);  // kv (M x 1024, spans S2+S3)
    unsigned short* S3 = (unsigned short*)(sbase + 5 * SZ);
    unsigned short* S4 = (unsigned short*)(sbase + 6 * SZ);  // q; later h
    unsigned short* S5 = (unsigned short*)(sbase + 7 * SZ);  // stats/prep, then ctx

    // small fp32 scratch at head of S5 (ctx written only after all consumers ran)
    float* stf  = (float*)(sbase + 7 * SZ);
    float* sumE = stf;             // enc row sums   [40960]
    float* ssqE = stf + 40960;
    float* sumD = stf + 81920;     // dec row sums
    float* ssqD = stf + 122880;
    float* rs_q  = stf + 163840;   // [512]
    float* b_q   = stf + 164352;   // [512]
    float* rs_kv = stf + 164864;   // [1024]
    float* b_kv  = stf + 165888;   // [1024]

    dim3 blk(256);
    dim3 g512(JDIM / 128, M_TOT / 128);     // (4, 320)  nwg=1280
    dim3 g1024(1024 / 128, M_TOT / 128);    // (8, 320)  nwg=2560
    dim3 gout(VPAD / 128, M_TOT / 128);     // (16, 320) nwg=5120

    prep_kernel<<<22144, blk, 0, stream>>>(
        We, Wd, Wq, Wk, Wv, Wo, Wout, g_q, beta_q, g_kv, beta_kv,
        bq, bk, bv, enc_in, dec_in, WB, EB, DB, stf, rs_q, b_q, rs_kv, b_kv);

    // input projections + row-stat accumulation
    gemm_bt<6, 512, false><<<g512, blk, 0, stream>>>(EB, WeB, be, S0, nullptr,
                                                     sumE, ssqE, nullptr);
    gemm_bt<6, 512, false><<<g512, blk, 0, stream>>>(DB, WdB, bd, S1, nullptr,
                                                     sumD, ssqD, nullptr);

    // LN-folded projections: q from decO, [k|v] from encO
    gemm_bt<4, 512, false><<<g512, blk, 0, stream>>>(S1, WqB, b_q, S4, nullptr,
                                                     sumD, ssqD, rs_q);
    gemm_bt<4, 1024, false><<<g1024, blk, 0, stream>>>(S0, WkB, b_kv, S2, nullptr,
                                                       sumE, ssqE, rs_kv);

    attn_kernel<<<M_TOT / 4, blk, 0, stream>>>(S4, S2, S5);

    gemm_bt<2, 512, false><<<g512, blk, 0, stream>>>(S5, WoB, bo, S3, S1,
                                                     nullptr, nullptr, nullptr);

    gemm_bt<3, 2000, true><<<gout, blk, 0, stream>>>(S3, WoutB, bout, out, nullptr,
                                                     nullptr, nullptr, nullptr);
}

// Round 3
// 871.865 us; speedup vs baseline: 1.0513x; 1.0513x over previous
//
#include <hip/hip_runtime.h>
#include <stdint.h>

// ---------------------------------------------------------------------------
// SigmoidAttentionJoiner on MI355X (gfx950)
// M = N*T*S = 16*512*5 = 40960 rows, J = 512, V = 2000 (padded to 2048)
// GEMMs: bf16 MFMA 16x16x32, 128x128 tile, BK=32, 256 threads — m97 structure.
//
// R3: - revert R2 pre-conversion (in-GEMM A32 staging is free; pre-pass cost
//       +28 µs of pure HBM traffic)
//     - enc+dec projections merged into ONE launch; q+kv merged into ONE
//       launch (part-select on blockIdx.x) -> 6 dispatches total
//     - ctx never materialized: tiny attn-dot kernel writes sg[row,head]
//       (1.3 MB); Wo-GEMM stages A = sg * v on the fly (saves ~84 MB)
//     - fast tanh via __expf in Wo epilogue
// ---------------------------------------------------------------------------

typedef __attribute__((ext_vector_type(8))) __bf16 bf16x8;
typedef __attribute__((ext_vector_type(4))) float float4v;
typedef __attribute__((ext_vector_type(8))) unsigned short ushort8;

static constexpr int M_TOT = 16 * 512 * 5;   // 40960
static constexpr int VOUT  = 2000;
static constexpr int VPAD  = 2048;

#define DI __device__ __forceinline__

DI float bf2f(unsigned short u) {
    union { unsigned int i; float f; } w; w.i = ((unsigned int)u) << 16; return w.f;
}
DI unsigned short f2bf(float f) {
    union { float f; unsigned int i; } w; w.f = f;
    return (unsigned short)((w.i + 0x8000u) >> 16);   // round-to-nearest
}

// async global->LDS, 16B per lane (wave-uniform LDS base + lane*16; our chunk
// indexing is lane-contiguous so this is safe — m104 caveat).
DI void gld_lds16(const void* g, void* l) {
    __builtin_amdgcn_global_load_lds(
        reinterpret_cast<__attribute__((address_space(1))) void*>(
            reinterpret_cast<uintptr_t>(g)),
        reinterpret_cast<__attribute__((address_space(3))) void*>(
            reinterpret_cast<uintptr_t>(l)),
        16, 0, 0);
}

// ---------------------------------------------------------------------------
// Core GEMM body: C[m,n] = sum_k A[m,k]*B[n,k] (+ epilogue). B^T = (out,in).
// AMODE 0: A bf16, global_load_lds
// AMODE 1: A fp32, convert during LDS staging
// AMODE 2: A = sg[row,head] * v  (v = kv[row][512+k], ctx on the fly)
// EPI 2: store bf16 tanh(dres + acc + bias), ldC
// EPI 3: store fp32 acc + bias, mask col < nout
// EPI 4: LN-affine: bf16( rstd*acc + (-mu*rstd)*rs[col] + bias[col] )
// EPI 6: store bf16(acc+bias); atomically accumulate row sum/ssq
// ---------------------------------------------------------------------------
template <int EPI, int AMODE>
DI void gemm_core(unsigned short* __restrict__ As, unsigned short* __restrict__ Bs,
                  const void* __restrict__ Ap, const unsigned short* __restrict__ B,
                  const float* __restrict__ bias, void* __restrict__ Cp,
                  int ldC, int nout, int m0, int n0,
                  const unsigned short* __restrict__ dres,
                  float* __restrict__ st_sum, float* __restrict__ st_ssq,
                  const float* __restrict__ rs, const float* __restrict__ sg)
{
    constexpr int K = 512, BK = 32;
    const int tid  = threadIdx.x;
    const int wave = tid >> 6;
    const int lane = tid & 63;
    const int wm   = wave >> 1;      // 0..1
    const int wn   = wave & 1;       // 0..1
    const int quad = lane >> 4;      // 0..3
    const int l16  = lane & 15;

    float4v acc[4][4];
#pragma unroll
    for (int i = 0; i < 4; i++)
#pragma unroll
        for (int j = 0; j < 4; j++)
            acc[i][j] = {0.f, 0.f, 0.f, 0.f};

    const int c0 = tid, c1 = tid + 256;
    const int ar0 = c0 >> 2, ac0 = (c0 & 3) * 8;
    const int ar1 = c1 >> 2, ac1 = (c1 & 3) * 8;

    for (int k0 = 0; k0 < K; k0 += BK) {
        gld_lds16(&B[(size_t)(n0 + ar0) * K + k0 + ac0], &Bs[c0 * 8]);
        gld_lds16(&B[(size_t)(n0 + ar1) * K + k0 + ac1], &Bs[c1 * 8]);
        if constexpr (AMODE == 0) {
            const unsigned short* Ab = (const unsigned short*)Ap;
            gld_lds16(&Ab[(size_t)(m0 + ar0) * K + k0 + ac0], &As[c0 * 8]);
            gld_lds16(&Ab[(size_t)(m0 + ar1) * K + k0 + ac1], &As[c1 * 8]);
        } else if constexpr (AMODE == 1) {
            const float* Af = (const float*)Ap;
            const float* p0 = &Af[(size_t)(m0 + ar0) * K + k0 + ac0];
            const float* p1 = &Af[(size_t)(m0 + ar1) * K + k0 + ac1];
            float4 f0 = *(const float4*)p0;
            float4 f1 = *(const float4*)(p0 + 4);
            float4 g0 = *(const float4*)p1;
            float4 g1 = *(const float4*)(p1 + 4);
            ushort8 u0, u1;
            u0[0] = f2bf(f0.x); u0[1] = f2bf(f0.y); u0[2] = f2bf(f0.z); u0[3] = f2bf(f0.w);
            u0[4] = f2bf(f1.x); u0[5] = f2bf(f1.y); u0[6] = f2bf(f1.z); u0[7] = f2bf(f1.w);
            u1[0] = f2bf(g0.x); u1[1] = f2bf(g0.y); u1[2] = f2bf(g0.z); u1[3] = f2bf(g0.w);
            u1[4] = f2bf(g1.x); u1[5] = f2bf(g1.y); u1[6] = f2bf(g1.z); u1[7] = f2bf(g1.w);
            *reinterpret_cast<ushort8*>(&As[c0 * 8]) = u0;
            *reinterpret_cast<ushort8*>(&As[c1 * 8]) = u1;
        } else {
            // ctx = sg[row,head] * v; v at kv[row*1024 + 512 + k]
            const unsigned short* kvb = (const unsigned short*)Ap;
            {
                int row = m0 + ar0;
                float s = sg[row * 8 + ((k0 + ac0) >> 6)];
                ushort8 uv = *reinterpret_cast<const ushort8*>(
                    &kvb[(size_t)row * 1024 + 512 + k0 + ac0]);
                ushort8 u;
#pragma unroll
                for (int j = 0; j < 8; j++) u[j] = f2bf(s * bf2f(uv[j]));
                *reinterpret_cast<ushort8*>(&As[c0 * 8]) = u;
            }
            {
                int row = m0 + ar1;
                float s = sg[row * 8 + ((k0 + ac1) >> 6)];
                ushort8 uv = *reinterpret_cast<const ushort8*>(
                    &kvb[(size_t)row * 1024 + 512 + k0 + ac1]);
                ushort8 u;
#pragma unroll
                for (int j = 0; j < 8; j++) u[j] = f2bf(s * bf2f(uv[j]));
                *reinterpret_cast<ushort8*>(&As[c1 * 8]) = u;
            }
        }
        __syncthreads();

        bf16x8 af[4], bfv[4];
#pragma unroll
        for (int i = 0; i < 4; i++)
            af[i] = *reinterpret_cast<const bf16x8*>(
                &As[(wm * 64 + i * 16 + l16) * BK + quad * 8]);
#pragma unroll
        for (int j = 0; j < 4; j++)
            bfv[j] = *reinterpret_cast<const bf16x8*>(
                &Bs[(wn * 64 + j * 16 + l16) * BK + quad * 8]);
#pragma unroll
        for (int i = 0; i < 4; i++)
#pragma unroll
            for (int j = 0; j < 4; j++)
                acc[i][j] = __builtin_amdgcn_mfma_f32_16x16x32_bf16(
                    af[i], bfv[j], acc[i][j], 0, 0, 0);
        __syncthreads();
    }

    float bias_v[4], rs_v[4];
#pragma unroll
    for (int j = 0; j < 4; j++) {
        int col = n0 + wn * 64 + j * 16 + l16;
        bias_v[j] = (col < nout) ? bias[col] : 0.f;
        if constexpr (EPI == 4) rs_v[j] = rs[col];
    }

    if constexpr (EPI == 4) {
#pragma unroll
        for (int i = 0; i < 4; i++) {
            int rbase = m0 + wm * 64 + i * 16 + quad * 4;
#pragma unroll
            for (int r = 0; r < 4; r++) {
                int row = rbase + r;
                float s  = st_sum[row];
                float s2 = st_ssq[row];
                float mean = s * (1.f / 512.f);
                float var  = s2 * (1.f / 512.f) - mean * mean;
                float rstd = rsqrtf(var + 1e-5f);
                float crow = -mean * rstd;
#pragma unroll
                for (int j = 0; j < 4; j++) {
                    int col = n0 + wn * 64 + j * 16 + l16;
                    float val = fmaf(rstd, acc[i][j][r],
                                fmaf(crow, rs_v[j], bias_v[j]));
                    ((unsigned short*)Cp)[(size_t)row * ldC + col] = f2bf(val);
                }
            }
        }
    } else {
#pragma unroll
        for (int i = 0; i < 4; i++) {
            int rbase = m0 + wm * 64 + i * 16 + quad * 4;
#pragma unroll
            for (int j = 0; j < 4; j++) {
                int col = n0 + wn * 64 + j * 16 + l16;
#pragma unroll
                for (int r = 0; r < 4; r++) {
                    float val = acc[i][j][r] + bias_v[j];
                    int row = rbase + r;
                    if constexpr (EPI == 2) {
                        float t = bf2f(dres[(size_t)row * 512 + col]) + val;
                        // fast tanh: 1 - 2/(e^{2t}+1)  (exact at +-inf)
                        float th = 1.f - 2.f / (__expf(t + t) + 1.f);
                        ((unsigned short*)Cp)[(size_t)row * ldC + col] = f2bf(th);
                    } else if constexpr (EPI == 3) {
                        if (col < nout)
                            ((float*)Cp)[(size_t)row * ldC + col] = val;
                    } else {  // EPI == 6
                        ((unsigned short*)Cp)[(size_t)row * ldC + col] = f2bf(val);
                    }
                }
            }
        }
    }

    if constexpr (EPI == 6) {
#pragma unroll
        for (int i = 0; i < 4; i++) {
#pragma unroll
            for (int r = 0; r < 4; r++) {
                float ps = 0.f, ps2 = 0.f;
#pragma unroll
                for (int j = 0; j < 4; j++) {
                    float v = acc[i][j][r] + bias_v[j];
                    ps += v;
                    ps2 = fmaf(v, v, ps2);
                }
#pragma unroll
                for (int m = 1; m < 16; m <<= 1) {
                    ps  += __shfl_xor(ps,  m, 64);
                    ps2 += __shfl_xor(ps2, m, 64);
                }
                if (l16 == 0) {
                    int row = m0 + wm * 64 + i * 16 + quad * 4 + r;
                    atomicAdd(&st_sum[row], ps);
                    atomicAdd(&st_ssq[row], ps2);
                }
            }
        }
    }
}

// ---------------------------------------------------------------------------
// merged enc+dec projection: grid (8, 320); x<4 -> enc, x>=4 -> dec. A32+EPI6.
// ---------------------------------------------------------------------------
__global__ __launch_bounds__(256) void k_projED(
    const float* __restrict__ enc_in, const float* __restrict__ dec_in,
    const unsigned short* __restrict__ WeB, const unsigned short* __restrict__ WdB,
    const float* __restrict__ be, const float* __restrict__ bd,
    unsigned short* __restrict__ S0, unsigned short* __restrict__ S1,
    float* __restrict__ sumE, float* __restrict__ ssqE,
    float* __restrict__ sumD, float* __restrict__ ssqD)
{
    __shared__ unsigned short As[128 * 32];
    __shared__ unsigned short Bs[128 * 32];
    const bool isDec = blockIdx.x >= 4;
    const int  bx    = blockIdx.x - (isDec ? 4 : 0);
    gemm_core<6, 1>(As, Bs,
                    isDec ? (const void*)dec_in : (const void*)enc_in,
                    isDec ? WdB : WeB, isDec ? bd : be,
                    isDec ? (void*)S1 : (void*)S0,
                    512, 512, blockIdx.y * 128, bx * 128,
                    nullptr,
                    isDec ? sumD : sumE, isDec ? ssqD : ssqE,
                    nullptr, nullptr);
}

// ---------------------------------------------------------------------------
// merged q + kv LN-folded projection: grid (12, 320); x<4 -> q, x>=4 -> kv.
// ---------------------------------------------------------------------------
__global__ __launch_bounds__(256) void k_qkv(
    const unsigned short* __restrict__ S1, const unsigned short* __restrict__ S0,
    const unsigned short* __restrict__ WqB, const unsigned short* __restrict__ WkvB,
    const float* __restrict__ b_q, const float* __restrict__ b_kv,
    unsigned short* __restrict__ Sq, unsigned short* __restrict__ Skv,
    float* __restrict__ sumD, float* __restrict__ ssqD,
    float* __restrict__ sumE, float* __restrict__ ssqE,
    const float* __restrict__ rs_q, const float* __restrict__ rs_kv)
{
    __shared__ unsigned short As[128 * 32];
    __shared__ unsigned short Bs[128 * 32];
    const bool isKV = blockIdx.x >= 4;
    const int  bx   = blockIdx.x - (isKV ? 4 : 0);
    gemm_core<4, 0>(As, Bs,
                    isKV ? (const void*)S0 : (const void*)S1,
                    isKV ? WkvB : WqB, isKV ? b_kv : b_q,
                    isKV ? (void*)Skv : (void*)Sq,
                    isKV ? 1024 : 512, isKV ? 1024 : 512,
                    blockIdx.y * 128, bx * 128,
                    nullptr,
                    isKV ? sumE : sumD, isKV ? ssqE : ssqD,
                    isKV ? rs_kv : rs_q, nullptr);
}

// ---------------------------------------------------------------------------
// Wo GEMM with on-the-fly ctx staging (A = sg * v), tanh(dres + .) epilogue
// ---------------------------------------------------------------------------
__global__ __launch_bounds__(256) void k_ctxo(
    const unsigned short* __restrict__ kv, const float* __restrict__ sg,
    const unsigned short* __restrict__ WoB, const float* __restrict__ bo,
    unsigned short* __restrict__ H, const unsigned short* __restrict__ dres)
{
    __shared__ unsigned short As[128 * 32];
    __shared__ unsigned short Bs[128 * 32];
    gemm_core<2, 2>(As, Bs, kv, WoB, bo, H, 512, 512,
                    blockIdx.y * 128, blockIdx.x * 128,
                    dres, nullptr, nullptr, nullptr, sg);
}

// ---------------------------------------------------------------------------
// vocab GEMM, fp32 out, XCD-chunked swizzle (nwg = 5120, %8 == 0)
// ---------------------------------------------------------------------------
__global__ __launch_bounds__(256) void k_out(
    const unsigned short* __restrict__ H, const unsigned short* __restrict__ WoutB,
    const float* __restrict__ bout, float* __restrict__ out)
{
    __shared__ unsigned short As[128 * 32];
    __shared__ unsigned short Bs[128 * 32];
    const int gx  = gridDim.x;
    const int nwg = gx * gridDim.y;
    const int id  = blockIdx.x + gx * blockIdx.y;
    const int logical = (id & 7) * (nwg >> 3) + (id >> 3);
    gemm_core<3, 0>(As, Bs, H, WoutB, bout, out, VOUT, VOUT,
                    (logical / gx) * 128, (logical % gx) * 128,
                    nullptr, nullptr, nullptr, nullptr, nullptr);
}

// ---------------------------------------------------------------------------
// Fused prep: blocks [0,1280) weights->bf16 (+zero stats), [1280,1664) LN-prep
// ---------------------------------------------------------------------------
__global__ __launch_bounds__(256) void prep_kernel(
    const float* __restrict__ We, const float* __restrict__ Wd,
    const float* __restrict__ Wq, const float* __restrict__ Wk,
    const float* __restrict__ Wv, const float* __restrict__ Wo,
    const float* __restrict__ Wout,
    const float* __restrict__ g_q, const float* __restrict__ beta_q,
    const float* __restrict__ g_kv, const float* __restrict__ beta_kv,
    const float* __restrict__ bq, const float* __restrict__ bk,
    const float* __restrict__ bv,
    unsigned short* __restrict__ WB, float* __restrict__ stz,
    float* __restrict__ rs_q, float* __restrict__ b_q,
    float* __restrict__ rs_kv, float* __restrict__ b_kv)
{
    const int b   = blockIdx.x;
    const int tid = threadIdx.x;

    if (b < 1280) {
        if (b < 768) {
            const int seg = b >> 7;                      // 0..5
            const int off = (b & 127) * 2048 + tid * 8;
            const float* src = seg == 0 ? We : seg == 1 ? Wd : seg == 2 ? Wq
                             : seg == 3 ? Wk : seg == 4 ? Wv : Wo;
            float4 f0 = *(const float4*)&src[off];
            float4 f1 = *(const float4*)&src[off + 4];
            float sc[8] = {1,1,1,1,1,1,1,1};
            if (seg >= 2 && seg <= 4) {
                const float* g = (seg == 2) ? g_q : g_kv;
                int j0 = off & 511;
                float4 s0 = *(const float4*)&g[j0];
                float4 s1 = *(const float4*)&g[j0 + 4];
                sc[0]=s0.x; sc[1]=s0.y; sc[2]=s0.z; sc[3]=s0.w;
                sc[4]=s1.x; sc[5]=s1.y; sc[6]=s1.z; sc[7]=s1.w;
            }
            ushort8 u;
            u[0]=f2bf(f0.x*sc[0]); u[1]=f2bf(f0.y*sc[1]); u[2]=f2bf(f0.z*sc[2]); u[3]=f2bf(f0.w*sc[3]);
            u[4]=f2bf(f1.x*sc[4]); u[5]=f2bf(f1.y*sc[5]); u[6]=f2bf(f1.z*sc[6]); u[7]=f2bf(f1.w*sc[7]);
            *reinterpret_cast<ushort8*>(&WB[(size_t)b * 2048 + tid * 8]) = u;
        } else {
            const int rem = (b - 768) * 2048 + tid * 8;
            const int row = rem >> 9;
            ushort8 u;
            if (row < VOUT) {
                float4 f0 = *(const float4*)&Wout[rem];
                float4 f1 = *(const float4*)&Wout[rem + 4];
                u[0]=f2bf(f0.x); u[1]=f2bf(f0.y); u[2]=f2bf(f0.z); u[3]=f2bf(f0.w);
                u[4]=f2bf(f1.x); u[5]=f2bf(f1.y); u[6]=f2bf(f1.z); u[7]=f2bf(f1.w);
            } else {
                u = (ushort8)0;
            }
            *reinterpret_cast<ushort8*>(&WB[1572864 + (size_t)(b - 768) * 2048 + tid * 8]) = u;
        }
        int z = b * 256 + tid;
        if (z < 163840) stz[z] = 0.f;
    } else {
        const int idx  = (b - 1280) * 4 + (tid >> 6);   // 0..1535
        const int lane = tid & 63;
        const float *W, *g, *bt, *bb; float *rs_out, *b_out; int r;
        if (idx < 512)       { W = Wq; g = g_q;  bt = beta_q;  bb = bq;
                               rs_out = &rs_q[idx];        b_out = &b_q[idx];        r = idx; }
        else if (idx < 1024) { W = Wk; g = g_kv; bt = beta_kv; bb = bk;
                               rs_out = &rs_kv[idx - 512]; b_out = &b_kv[idx - 512]; r = idx - 512; }
        else                 { W = Wv; g = g_kv; bt = beta_kv; bb = bv;
                               rs_out = &rs_kv[idx - 512]; b_out = &b_kv[idx - 512]; r = idx - 1024; }

        const float* wr = &W[(size_t)r * 512];
        float s = 0.f, sb = 0.f;
        int j0 = lane * 8;
        float4 w0 = *(const float4*)&wr[j0];
        float4 w1 = *(const float4*)&wr[j0 + 4];
        float4 ga = *(const float4*)&g[j0];
        float4 gb = *(const float4*)&g[j0 + 4];
        float4 ba = *(const float4*)&bt[j0];
        float4 bb4 = *(const float4*)&bt[j0 + 4];
        s  += w0.x * ga.x + w0.y * ga.y + w0.z * ga.z + w0.w * ga.w;
        s  += w1.x * gb.x + w1.y * gb.y + w1.z * gb.z + w1.w * gb.w;
        sb += w0.x * ba.x + w0.y * ba.y + w0.z * ba.z + w0.w * ba.w;
        sb += w1.x * bb4.x + w1.y * bb4.y + w1.z * bb4.z + w1.w * bb4.w;
#pragma unroll
        for (int m = 1; m < 64; m <<= 1) {
            s  += __shfl_xor(s,  m, 64);
            sb += __shfl_xor(sb, m, 64);
        }
        if (lane == 0) { *rs_out = s; *b_out = bb[r] + sb; }
    }
}

// ---------------------------------------------------------------------------
// attn dot: sg[row,head] = sigmoid(dot(q_h,k_h)/8); one wave per row
// ---------------------------------------------------------------------------
__global__ __launch_bounds__(256) void attnq_kernel(
    const unsigned short* __restrict__ q, const unsigned short* __restrict__ kv,
    float* __restrict__ sg)
{
    int row  = blockIdx.x * 4 + (threadIdx.x >> 6);
    int lane = threadIdx.x & 63;
    ushort8 uq = *reinterpret_cast<const ushort8*>(&q[(size_t)row * 512 + lane * 8]);
    ushort8 uk = *reinterpret_cast<const ushort8*>(&kv[(size_t)row * 1024 + lane * 8]);
    float dot = 0.f;
#pragma unroll
    for (int j = 0; j < 8; j++) dot += bf2f(uq[j]) * bf2f(uk[j]);
    dot += __shfl_xor(dot, 1, 64);
    dot += __shfl_xor(dot, 2, 64);
    dot += __shfl_xor(dot, 4, 64);
    if ((lane & 7) == 0)
        sg[(size_t)row * 8 + (lane >> 3)] = 1.f / (1.f + __expf(-dot * 0.125f));
}

// ---------------------------------------------------------------------------
extern "C" void kernel_launch(void* const* d_in, const int* in_sizes, int n_in,
                              void* d_out, int out_size, void* d_ws, size_t ws_size,
                              hipStream_t stream)
{
    (void)in_sizes; (void)n_in; (void)out_size; (void)ws_size;
    const float* enc_in  = (const float*)d_in[0];
    const float* dec_in  = (const float*)d_in[1];
    const float* We      = (const float*)d_in[2];  const float* be     = (const float*)d_in[3];
    const float* Wd      = (const float*)d_in[4];  const float* bd     = (const float*)d_in[5];
    const float* g_q     = (const float*)d_in[6];  const float* beta_q = (const float*)d_in[7];
    const float* g_kv    = (const float*)d_in[8];  const float* beta_kv= (const float*)d_in[9];
    const float* Wq      = (const float*)d_in[10]; const float* bq     = (const float*)d_in[11];
    const float* Wk      = (const float*)d_in[12]; const float* bk     = (const float*)d_in[13];
    const float* Wv      = (const float*)d_in[14]; const float* bv     = (const float*)d_in[15];
    const float* Wo      = (const float*)d_in[16]; const float* bo     = (const float*)d_in[17];
    const float* Wout    = (const float*)d_in[18]; const float* bout   = (const float*)d_in[19];
    float* out = (float*)d_out;

    // bf16 weight buffer layout (elements)
    unsigned short* WB    = (unsigned short*)d_ws;
    unsigned short* WeB   = WB + 0;
    unsigned short* WdB   = WB + 262144;
    unsigned short* WqB   = WB + 524288;
    unsigned short* WkvB  = WB + 786432;   // Wk then Wv contiguous => N=1024
    unsigned short* WoB   = WB + 1310720;
    unsigned short* WoutB = WB + 1572864;  // 2048 x 512 (zero-padded rows)

    // six aliased M x 512 bf16 slots
    char* sbase = (char*)d_ws + 5242880;
    const size_t SZ = (size_t)M_TOT * 512 * 2;   // 41,943,040 B
    unsigned short* S0 = (unsigned short*)(sbase + 0 * SZ);  // encO
    unsigned short* S1 = (unsigned short*)(sbase + 1 * SZ);  // decO (live to tanh)
    unsigned short* S2 = (unsigned short*)(sbase + 2 * SZ);  // kv (M x 1024, spans S2+S3)
    unsigned short* S4 = (unsigned short*)(sbase + 4 * SZ);  // q, then h
    unsigned short* S5 = (unsigned short*)(sbase + 5 * SZ);  // fp32 scratch

    float* stf  = (float*)S5;
    float* sumE = stf;             // enc row sums   [40960]
    float* ssqE = stf + 40960;
    float* sumD = stf + 81920;     // dec row sums
    float* ssqD = stf + 122880;
    float* rs_q  = stf + 163840;   // [512]
    float* b_q   = stf + 164352;   // [512]
    float* rs_kv = stf + 164864;   // [1024]
    float* b_kv  = stf + 165888;   // [1024]
    float* sg    = stf + 166912;   // [40960*8]

    dim3 blk(256);

    prep_kernel<<<1664, blk, 0, stream>>>(
        We, Wd, Wq, Wk, Wv, Wo, Wout, g_q, beta_q, g_kv, beta_kv,
        bq, bk, bv, WB, stf, rs_q, b_q, rs_kv, b_kv);

    // enc + dec projections (A32) + row stats, one launch
    k_projED<<<dim3(8, 320), blk, 0, stream>>>(
        enc_in, dec_in, WeB, WdB, be, bd, S0, S1, sumE, ssqE, sumD, ssqD);

    // LN-folded q + kv, one launch
    k_qkv<<<dim3(12, 320), blk, 0, stream>>>(
        S1, S0, WqB, WkvB, b_q, b_kv, S4, S2,
        sumD, ssqD, sumE, ssqE, rs_q, rs_kv);

    // per-row, per-head sigmoid dots
    attnq_kernel<<<M_TOT / 4, blk, 0, stream>>>(S4, S2, sg);

    // Wo GEMM with ctx staged on the fly; h = tanh(decO + .) -> S4
    k_ctxo<<<dim3(4, 320), blk, 0, stream>>>(S2, sg, WoB, bo, S4, S1);

    // vocab projection
    k_out<<<dim3(16, 320), blk, 0, stream>>>(S4, WoutB, bout, out);
}

// Round 4
// 853.565 us; speedup vs baseline: 1.0739x; 1.0214x over previous
//
#include <hip/hip_runtime.h>
#include <stdint.h>

// ---------------------------------------------------------------------------
// SigmoidAttentionJoiner on MI355X (gfx950)
// M = N*T*S = 16*512*5 = 40960 rows, J = 512, V = 2000 (padded to 2048)
// GEMMs: bf16 MFMA 16x16x32, 128x128 tile, 256 threads — m97 structure.
//
// R4: BK=64 (two stacked [128][32] LDS sub-tiles -> fragment reads keep the
//     proven conflict-free wave-contiguous pattern). Halves the number of
//     __syncthreads + vmcnt(0) drains per block (32 -> 16), which is the
//     structural stall of this template; K=512 gives only 8 K-steps now.
//     Everything else identical to R3 (6 dispatches, ctx on-the-fly, LN fold).
// ---------------------------------------------------------------------------

typedef __attribute__((ext_vector_type(8))) __bf16 bf16x8;
typedef __attribute__((ext_vector_type(4))) float float4v;
typedef __attribute__((ext_vector_type(8))) unsigned short ushort8;

static constexpr int M_TOT = 16 * 512 * 5;   // 40960
static constexpr int VOUT  = 2000;
static constexpr int VPAD  = 2048;

#define DI __device__ __forceinline__

DI float bf2f(unsigned short u) {
    union { unsigned int i; float f; } w; w.i = ((unsigned int)u) << 16; return w.f;
}
DI unsigned short f2bf(float f) {
    union { float f; unsigned int i; } w; w.f = f;
    return (unsigned short)((w.i + 0x8000u) >> 16);   // round-to-nearest
}

// async global->LDS, 16B per lane (wave-uniform LDS base + lane*16; our chunk
// indexing is lane-contiguous so this is safe — m104 caveat).
DI void gld_lds16(const void* g, void* l) {
    __builtin_amdgcn_global_load_lds(
        reinterpret_cast<__attribute__((address_space(1))) void*>(
            reinterpret_cast<uintptr_t>(g)),
        reinterpret_cast<__attribute__((address_space(3))) void*>(
            reinterpret_cast<uintptr_t>(l)),
        16, 0, 0);
}

// ---------------------------------------------------------------------------
// Core GEMM body: C[m,n] = sum_k A[m,k]*B[n,k] (+ epilogue). B^T = (out,in).
// K-tile = 64, stored as two [128][32] halves: LDS offset = ch*8 shorts where
// chunk ch in [0,1024): half = ch>>9, row = (ch>>2)&127, col8 = ch&3
//   global col = (ch>>9)*32 + (ch&3)*8
// Fragment read (half kk, row r, quad q): kk*4096 + r*32 + q*8 — the wave's
// 64 lanes cover a contiguous 1KB region -> conflict-free (as in BK=32).
// AMODE 0: A bf16, global_load_lds
// AMODE 1: A fp32, convert during LDS staging
// AMODE 2: A = sg[row,head] * v  (v = kv[row][512+k], ctx on the fly)
// EPI 2: store bf16 tanh(dres + acc + bias), ldC
// EPI 3: store fp32 acc + bias, mask col < nout
// EPI 4: LN-affine: bf16( rstd*acc + (-mu*rstd)*rs[col] + bias[col] )
// EPI 6: store bf16(acc+bias); atomically accumulate row sum/ssq
// ---------------------------------------------------------------------------
template <int EPI, int AMODE>
DI void gemm_core(unsigned short* __restrict__ As, unsigned short* __restrict__ Bs,
                  const void* __restrict__ Ap, const unsigned short* __restrict__ B,
                  const float* __restrict__ bias, void* __restrict__ Cp,
                  int ldC, int nout, int m0, int n0,
                  const unsigned short* __restrict__ dres,
                  float* __restrict__ st_sum, float* __restrict__ st_ssq,
                  const float* __restrict__ rs, const float* __restrict__ sg)
{
    constexpr int K = 512, BK = 64;
    const int tid  = threadIdx.x;
    const int wave = tid >> 6;
    const int lane = tid & 63;
    const int wm   = wave >> 1;      // 0..1
    const int wn   = wave & 1;       // 0..1
    const int quad = lane >> 4;      // 0..3
    const int l16  = lane & 15;

    float4v acc[4][4];
#pragma unroll
    for (int i = 0; i < 4; i++)
#pragma unroll
        for (int j = 0; j < 4; j++)
            acc[i][j] = {0.f, 0.f, 0.f, 0.f};

    for (int k0 = 0; k0 < K; k0 += BK) {
        // ---- stage B: 4 chunks/thread via global_load_lds ----
#pragma unroll
        for (int p = 0; p < 4; p++) {
            const int ch  = tid + p * 256;
            const int row = (ch >> 2) & 127;
            const int col = ((ch >> 9) << 5) + (ch & 3) * 8;
            gld_lds16(&B[(size_t)(n0 + row) * K + k0 + col], &Bs[ch * 8]);
        }
        // ---- stage A by mode ----
        if constexpr (AMODE == 0) {
            const unsigned short* Ab = (const unsigned short*)Ap;
#pragma unroll
            for (int p = 0; p < 4; p++) {
                const int ch  = tid + p * 256;
                const int row = (ch >> 2) & 127;
                const int col = ((ch >> 9) << 5) + (ch & 3) * 8;
                gld_lds16(&Ab[(size_t)(m0 + row) * K + k0 + col], &As[ch * 8]);
            }
        } else if constexpr (AMODE == 1) {
            const float* Af = (const float*)Ap;
#pragma unroll
            for (int p = 0; p < 4; p++) {
                const int ch  = tid + p * 256;
                const int row = (ch >> 2) & 127;
                const int col = ((ch >> 9) << 5) + (ch & 3) * 8;
                const float* src = &Af[(size_t)(m0 + row) * K + k0 + col];
                float4 f0 = *(const float4*)src;
                float4 f1 = *(const float4*)(src + 4);
                ushort8 u;
                u[0]=f2bf(f0.x); u[1]=f2bf(f0.y); u[2]=f2bf(f0.z); u[3]=f2bf(f0.w);
                u[4]=f2bf(f1.x); u[5]=f2bf(f1.y); u[6]=f2bf(f1.z); u[7]=f2bf(f1.w);
                *reinterpret_cast<ushort8*>(&As[ch * 8]) = u;
            }
        } else {
            // ctx = sg[row,head] * v; v at kv[row*1024 + 512 + k]
            const unsigned short* kvb = (const unsigned short*)Ap;
#pragma unroll
            for (int p = 0; p < 4; p++) {
                const int ch  = tid + p * 256;
                const int row = m0 + ((ch >> 2) & 127);
                const int col = k0 + ((ch >> 9) << 5) + (ch & 3) * 8;
                const float s = sg[row * 8 + (col >> 6)];
                ushort8 uv = *reinterpret_cast<const ushort8*>(
                    &kvb[(size_t)row * 1024 + 512 + col]);
                ushort8 u;
#pragma unroll
                for (int j = 0; j < 8; j++) u[j] = f2bf(s * bf2f(uv[j]));
                *reinterpret_cast<ushort8*>(&As[ch * 8]) = u;
            }
        }
        __syncthreads();

#pragma unroll
        for (int kk = 0; kk < 2; kk++) {
            bf16x8 af[4], bfv[4];
#pragma unroll
            for (int i = 0; i < 4; i++)
                af[i] = *reinterpret_cast<const bf16x8*>(
                    &As[kk * 4096 + (wm * 64 + i * 16 + l16) * 32 + quad * 8]);
#pragma unroll
            for (int j = 0; j < 4; j++)
                bfv[j] = *reinterpret_cast<const bf16x8*>(
                    &Bs[kk * 4096 + (wn * 64 + j * 16 + l16) * 32 + quad * 8]);
#pragma unroll
            for (int i = 0; i < 4; i++)
#pragma unroll
                for (int j = 0; j < 4; j++)
                    acc[i][j] = __builtin_amdgcn_mfma_f32_16x16x32_bf16(
                        af[i], bfv[j], acc[i][j], 0, 0, 0);
        }
        __syncthreads();
    }

    float bias_v[4], rs_v[4];
#pragma unroll
    for (int j = 0; j < 4; j++) {
        int col = n0 + wn * 64 + j * 16 + l16;
        bias_v[j] = (col < nout) ? bias[col] : 0.f;
        if constexpr (EPI == 4) rs_v[j] = rs[col];
    }

    if constexpr (EPI == 4) {
#pragma unroll
        for (int i = 0; i < 4; i++) {
            int rbase = m0 + wm * 64 + i * 16 + quad * 4;
#pragma unroll
            for (int r = 0; r < 4; r++) {
                int row = rbase + r;
                float s  = st_sum[row];
                float s2 = st_ssq[row];
                float mean = s * (1.f / 512.f);
                float var  = s2 * (1.f / 512.f) - mean * mean;
                float rstd = rsqrtf(var + 1e-5f);
                float crow = -mean * rstd;
#pragma unroll
                for (int j = 0; j < 4; j++) {
                    int col = n0 + wn * 64 + j * 16 + l16;
                    float val = fmaf(rstd, acc[i][j][r],
                                fmaf(crow, rs_v[j], bias_v[j]));
                    ((unsigned short*)Cp)[(size_t)row * ldC + col] = f2bf(val);
                }
            }
        }
    } else {
#pragma unroll
        for (int i = 0; i < 4; i++) {
            int rbase = m0 + wm * 64 + i * 16 + quad * 4;
#pragma unroll
            for (int j = 0; j < 4; j++) {
                int col = n0 + wn * 64 + j * 16 + l16;
#pragma unroll
                for (int r = 0; r < 4; r++) {
                    float val = acc[i][j][r] + bias_v[j];
                    int row = rbase + r;
                    if constexpr (EPI == 2) {
                        float t = bf2f(dres[(size_t)row * 512 + col]) + val;
                        // fast tanh: 1 - 2/(e^{2t}+1)  (exact at +-inf)
                        float th = 1.f - 2.f / (__expf(t + t) + 1.f);
                        ((unsigned short*)Cp)[(size_t)row * ldC + col] = f2bf(th);
                    } else if constexpr (EPI == 3) {
                        if (col < nout)
                            ((float*)Cp)[(size_t)row * ldC + col] = val;
                    } else {  // EPI == 6
                        ((unsigned short*)Cp)[(size_t)row * ldC + col] = f2bf(val);
                    }
                }
            }
        }
    }

    if constexpr (EPI == 6) {
#pragma unroll
        for (int i = 0; i < 4; i++) {
#pragma unroll
            for (int r = 0; r < 4; r++) {
                float ps = 0.f, ps2 = 0.f;
#pragma unroll
                for (int j = 0; j < 4; j++) {
                    float v = acc[i][j][r] + bias_v[j];
                    ps += v;
                    ps2 = fmaf(v, v, ps2);
                }
#pragma unroll
                for (int m = 1; m < 16; m <<= 1) {
                    ps  += __shfl_xor(ps,  m, 64);
                    ps2 += __shfl_xor(ps2, m, 64);
                }
                if (l16 == 0) {
                    int row = m0 + wm * 64 + i * 16 + quad * 4 + r;
                    atomicAdd(&st_sum[row], ps);
                    atomicAdd(&st_ssq[row], ps2);
                }
            }
        }
    }
}

// ---------------------------------------------------------------------------
// merged enc+dec projection: grid (8, 320); x<4 -> enc, x>=4 -> dec. A32+EPI6.
// ---------------------------------------------------------------------------
__global__ __launch_bounds__(256) void k_projED(
    const float* __restrict__ enc_in, const float* __restrict__ dec_in,
    const unsigned short* __restrict__ WeB, const unsigned short* __restrict__ WdB,
    const float* __restrict__ be, const float* __restrict__ bd,
    unsigned short* __restrict__ S0, unsigned short* __restrict__ S1,
    float* __restrict__ sumE, float* __restrict__ ssqE,
    float* __restrict__ sumD, float* __restrict__ ssqD)
{
    __shared__ unsigned short As[2 * 128 * 32];
    __shared__ unsigned short Bs[2 * 128 * 32];
    const bool isDec = blockIdx.x >= 4;
    const int  bx    = blockIdx.x - (isDec ? 4 : 0);
    gemm_core<6, 1>(As, Bs,
                    isDec ? (const void*)dec_in : (const void*)enc_in,
                    isDec ? WdB : WeB, isDec ? bd : be,
                    isDec ? (void*)S1 : (void*)S0,
                    512, 512, blockIdx.y * 128, bx * 128,
                    nullptr,
                    isDec ? sumD : sumE, isDec ? ssqD : ssqE,
                    nullptr, nullptr);
}

// ---------------------------------------------------------------------------
// merged q + kv LN-folded projection: grid (12, 320); x<4 -> q, x>=4 -> kv.
// ---------------------------------------------------------------------------
__global__ __launch_bounds__(256) void k_qkv(
    const unsigned short* __restrict__ S1, const unsigned short* __restrict__ S0,
    const unsigned short* __restrict__ WqB, const unsigned short* __restrict__ WkvB,
    const float* __restrict__ b_q, const float* __restrict__ b_kv,
    unsigned short* __restrict__ Sq, unsigned short* __restrict__ Skv,
    float* __restrict__ sumD, float* __restrict__ ssqD,
    float* __restrict__ sumE, float* __restrict__ ssqE,
    const float* __restrict__ rs_q, const float* __restrict__ rs_kv)
{
    __shared__ unsigned short As[2 * 128 * 32];
    __shared__ unsigned short Bs[2 * 128 * 32];
    const bool isKV = blockIdx.x >= 4;
    const int  bx   = blockIdx.x - (isKV ? 4 : 0);
    gemm_core<4, 0>(As, Bs,
                    isKV ? (const void*)S0 : (const void*)S1,
                    isKV ? WkvB : WqB, isKV ? b_kv : b_q,
                    isKV ? (void*)Skv : (void*)Sq,
                    isKV ? 1024 : 512, isKV ? 1024 : 512,
                    blockIdx.y * 128, bx * 128,
                    nullptr,
                    isKV ? sumE : sumD, isKV ? ssqE : ssqD,
                    isKV ? rs_kv : rs_q, nullptr);
}

// ---------------------------------------------------------------------------
// Wo GEMM with on-the-fly ctx staging (A = sg * v), tanh(dres + .) epilogue
// ---------------------------------------------------------------------------
__global__ __launch_bounds__(256) void k_ctxo(
    const unsigned short* __restrict__ kv, const float* __restrict__ sg,
    const unsigned short* __restrict__ WoB, const float* __restrict__ bo,
    unsigned short* __restrict__ H, const unsigned short* __restrict__ dres)
{
    __shared__ unsigned short As[2 * 128 * 32];
    __shared__ unsigned short Bs[2 * 128 * 32];
    gemm_core<2, 2>(As, Bs, kv, WoB, bo, H, 512, 512,
                    blockIdx.y * 128, blockIdx.x * 128,
                    dres, nullptr, nullptr, nullptr, sg);
}

// ---------------------------------------------------------------------------
// vocab GEMM, fp32 out, XCD-chunked swizzle (nwg = 5120, %8 == 0)
// ---------------------------------------------------------------------------
__global__ __launch_bounds__(256) void k_out(
    const unsigned short* __restrict__ H, const unsigned short* __restrict__ WoutB,
    const float* __restrict__ bout, float* __restrict__ out)
{
    __shared__ unsigned short As[2 * 128 * 32];
    __shared__ unsigned short Bs[2 * 128 * 32];
    const int gx  = gridDim.x;
    const int nwg = gx * gridDim.y;
    const int id  = blockIdx.x + gx * blockIdx.y;
    const int logical = (id & 7) * (nwg >> 3) + (id >> 3);
    gemm_core<3, 0>(As, Bs, H, WoutB, bout, out, VOUT, VOUT,
                    (logical / gx) * 128, (logical % gx) * 128,
                    nullptr, nullptr, nullptr, nullptr, nullptr);
}

// ---------------------------------------------------------------------------
// Fused prep: blocks [0,1280) weights->bf16 (+zero stats), [1280,1664) LN-prep
// ---------------------------------------------------------------------------
__global__ __launch_bounds__(256) void prep_kernel(
    const float* __restrict__ We, const float* __restrict__ Wd,
    const float* __restrict__ Wq, const float* __restrict__ Wk,
    const float* __restrict__ Wv, const float* __restrict__ Wo,
    const float* __restrict__ Wout,
    const float* __restrict__ g_q, const float* __restrict__ beta_q,
    const float* __restrict__ g_kv, const float* __restrict__ beta_kv,
    const float* __restrict__ bq, const float* __restrict__ bk,
    const float* __restrict__ bv,
    unsigned short* __restrict__ WB, float* __restrict__ stz,
    float* __restrict__ rs_q, float* __restrict__ b_q,
    float* __restrict__ rs_kv, float* __restrict__ b_kv)
{
    const int b   = blockIdx.x;
    const int tid = threadIdx.x;

    if (b < 1280) {
        if (b < 768) {
            const int seg = b >> 7;                      // 0..5
            const int off = (b & 127) * 2048 + tid * 8;
            const float* src = seg == 0 ? We : seg == 1 ? Wd : seg == 2 ? Wq
                             : seg == 3 ? Wk : seg == 4 ? Wv : Wo;
            float4 f0 = *(const float4*)&src[off];
            float4 f1 = *(const float4*)&src[off + 4];
            float sc[8] = {1,1,1,1,1,1,1,1};
            if (seg >= 2 && seg <= 4) {
                const float* g = (seg == 2) ? g_q : g_kv;
                int j0 = off & 511;
                float4 s0 = *(const float4*)&g[j0];
                float4 s1 = *(const float4*)&g[j0 + 4];
                sc[0]=s0.x; sc[1]=s0.y; sc[2]=s0.z; sc[3]=s0.w;
                sc[4]=s1.x; sc[5]=s1.y; sc[6]=s1.z; sc[7]=s1.w;
            }
            ushort8 u;
            u[0]=f2bf(f0.x*sc[0]); u[1]=f2bf(f0.y*sc[1]); u[2]=f2bf(f0.z*sc[2]); u[3]=f2bf(f0.w*sc[3]);
            u[4]=f2bf(f1.x*sc[4]); u[5]=f2bf(f1.y*sc[5]); u[6]=f2bf(f1.z*sc[6]); u[7]=f2bf(f1.w*sc[7]);
            *reinterpret_cast<ushort8*>(&WB[(size_t)b * 2048 + tid * 8]) = u;
        } else {
            const int rem = (b - 768) * 2048 + tid * 8;
            const int row = rem >> 9;
            ushort8 u;
            if (row < VOUT) {
                float4 f0 = *(const float4*)&Wout[rem];
                float4 f1 = *(const float4*)&Wout[rem + 4];
                u[0]=f2bf(f0.x); u[1]=f2bf(f0.y); u[2]=f2bf(f0.z); u[3]=f2bf(f0.w);
                u[4]=f2bf(f1.x); u[5]=f2bf(f1.y); u[6]=f2bf(f1.z); u[7]=f2bf(f1.w);
            } else {
                u = (ushort8)0;
            }
            *reinterpret_cast<ushort8*>(&WB[1572864 + (size_t)(b - 768) * 2048 + tid * 8]) = u;
        }
        int z = b * 256 + tid;
        if (z < 163840) stz[z] = 0.f;
    } else {
        const int idx  = (b - 1280) * 4 + (tid >> 6);   // 0..1535
        const int lane = tid & 63;
        const float *W, *g, *bt, *bb; float *rs_out, *b_out; int r;
        if (idx < 512)       { W = Wq; g = g_q;  bt = beta_q;  bb = bq;
                               rs_out = &rs_q[idx];        b_out = &b_q[idx];        r = idx; }
        else if (idx < 1024) { W = Wk; g = g_kv; bt = beta_kv; bb = bk;
                               rs_out = &rs_kv[idx - 512]; b_out = &b_kv[idx - 512]; r = idx - 512; }
        else                 { W = Wv; g = g_kv; bt = beta_kv; bb = bv;
                               rs_out = &rs_kv[idx - 512]; b_out = &b_kv[idx - 512]; r = idx - 1024; }

        const float* wr = &W[(size_t)r * 512];
        float s = 0.f, sb = 0.f;
        int j0 = lane * 8;
        float4 w0 = *(const float4*)&wr[j0];
        float4 w1 = *(const float4*)&wr[j0 + 4];
        float4 ga = *(const float4*)&g[j0];
        float4 gb = *(const float4*)&g[j0 + 4];
        float4 ba = *(const float4*)&bt[j0];
        float4 bb4 = *(const float4*)&bt[j0 + 4];
        s  += w0.x * ga.x + w0.y * ga.y + w0.z * ga.z + w0.w * ga.w;
        s  += w1.x * gb.x + w1.y * gb.y + w1.z * gb.z + w1.w * gb.w;
        sb += w0.x * ba.x + w0.y * ba.y + w0.z * ba.z + w0.w * ba.w;
        sb += w1.x * bb4.x + w1.y * bb4.y + w1.z * bb4.z + w1.w * bb4.w;
#pragma unroll
        for (int m = 1; m < 64; m <<= 1) {
            s  += __shfl_xor(s,  m, 64);
            sb += __shfl_xor(sb, m, 64);
        }
        if (lane == 0) { *rs_out = s; *b_out = bb[r] + sb; }
    }
}

// ---------------------------------------------------------------------------
// attn dot: sg[row,head] = sigmoid(dot(q_h,k_h)/8); one wave per row
// ---------------------------------------------------------------------------
__global__ __launch_bounds__(256) void attnq_kernel(
    const unsigned short* __restrict__ q, const unsigned short* __restrict__ kv,
    float* __restrict__ sg)
{
    int row  = blockIdx.x * 4 + (threadIdx.x >> 6);
    int lane = threadIdx.x & 63;
    ushort8 uq = *reinterpret_cast<const ushort8*>(&q[(size_t)row * 512 + lane * 8]);
    ushort8 uk = *reinterpret_cast<const ushort8*>(&kv[(size_t)row * 1024 + lane * 8]);
    float dot = 0.f;
#pragma unroll
    for (int j = 0; j < 8; j++) dot += bf2f(uq[j]) * bf2f(uk[j]);
    dot += __shfl_xor(dot, 1, 64);
    dot += __shfl_xor(dot, 2, 64);
    dot += __shfl_xor(dot, 4, 64);
    if ((lane & 7) == 0)
        sg[(size_t)row * 8 + (lane >> 3)] = 1.f / (1.f + __expf(-dot * 0.125f));
}

// ---------------------------------------------------------------------------
extern "C" void kernel_launch(void* const* d_in, const int* in_sizes, int n_in,
                              void* d_out, int out_size, void* d_ws, size_t ws_size,
                              hipStream_t stream)
{
    (void)in_sizes; (void)n_in; (void)out_size; (void)ws_size;
    const float* enc_in  = (const float*)d_in[0];
    const float* dec_in  = (const float*)d_in[1];
    const float* We      = (const float*)d_in[2];  const float* be     = (const float*)d_in[3];
    const float* Wd      = (const float*)d_in[4];  const float* bd     = (const float*)d_in[5];
    const float* g_q     = (const float*)d_in[6];  const float* beta_q = (const float*)d_in[7];
    const float* g_kv    = (const float*)d_in[8];  const float* beta_kv= (const float*)d_in[9];
    const float* Wq      = (const float*)d_in[10]; const float* bq     = (const float*)d_in[11];
    const float* Wk      = (const float*)d_in[12]; const float* bk     = (const float*)d_in[13];
    const float* Wv      = (const float*)d_in[14]; const float* bv     = (const float*)d_in[15];
    const float* Wo      = (const float*)d_in[16]; const float* bo     = (const float*)d_in[17];
    const float* Wout    = (const float*)d_in[18]; const float* bout   = (const float*)d_in[19];
    float* out = (float*)d_out;

    // bf16 weight buffer layout (elements)
    unsigned short* WB    = (unsigned short*)d_ws;
    unsigned short* WeB   = WB + 0;
    unsigned short* WdB   = WB + 262144;
    unsigned short* WqB   = WB + 524288;
    unsigned short* WkvB  = WB + 786432;   // Wk then Wv contiguous => N=1024
    unsigned short* WoB   = WB + 1310720;
    unsigned short* WoutB = WB + 1572864;  // 2048 x 512 (zero-padded rows)

    // six aliased M x 512 bf16 slots
    char* sbase = (char*)d_ws + 5242880;
    const size_t SZ = (size_t)M_TOT * 512 * 2;   // 41,943,040 B
    unsigned short* S0 = (unsigned short*)(sbase + 0 * SZ);  // encO
    unsigned short* S1 = (unsigned short*)(sbase + 1 * SZ);  // decO (live to tanh)
    unsigned short* S2 = (unsigned short*)(sbase + 2 * SZ);  // kv (M x 1024, spans S2+S3)
    unsigned short* S4 = (unsigned short*)(sbase + 4 * SZ);  // q, then h
    unsigned short* S5 = (unsigned short*)(sbase + 5 * SZ);  // fp32 scratch

    float* stf  = (float*)S5;
    float* sumE = stf;             // enc row sums   [40960]
    float* ssqE = stf + 40960;
    float* sumD = stf + 81920;     // dec row sums
    float* ssqD = stf + 122880;
    float* rs_q  = stf + 163840;   // [512]
    float* b_q   = stf + 164352;   // [512]
    float* rs_kv = stf + 164864;   // [1024]
    float* b_kv  = stf + 165888;   // [1024]
    float* sg    = stf + 166912;   // [40960*8]

    dim3 blk(256);

    prep_kernel<<<1664, blk, 0, stream>>>(
        We, Wd, Wq, Wk, Wv, Wo, Wout, g_q, beta_q, g_kv, beta_kv,
        bq, bk, bv, WB, stf, rs_q, b_q, rs_kv, b_kv);

    // enc + dec projections (A32) + row stats, one launch
    k_projED<<<dim3(8, 320), blk, 0, stream>>>(
        enc_in, dec_in, WeB, WdB, be, bd, S0, S1, sumE, ssqE, sumD, ssqD);

    // LN-folded q + kv, one launch
    k_qkv<<<dim3(12, 320), blk, 0, stream>>>(
        S1, S0, WqB, WkvB, b_q, b_kv, S4, S2,
        sumD, ssqD, sumE, ssqE, rs_q, rs_kv);

    // per-row, per-head sigmoid dots
    attnq_kernel<<<M_TOT / 4, blk, 0, stream>>>(S4, S2, sg);

    // Wo GEMM with ctx staged on the fly; h = tanh(decO + .) -> S4
    k_ctxo<<<dim3(4, 320), blk, 0, stream>>>(S2, sg, WoB, bo, S4, S1);

    // vocab projection
    k_out<<<dim3(16, 320), blk, 0, stream>>>(S4, WoutB, bout, out);
}